// Round 12
// baseline (234.992 us; speedup 1.0000x reference)
//
#include <hip/hip_runtime.h>
#include <hip/hip_bf16.h>

// CoarseGraining: y[i,b] = heg[b] * sum_j exp(-beta[j,b] * d2(i,j)) * wrho[j]
// N = M = 8192, NB = 16, WIDTH = 32. Inputs float32, output float32.
// R10: wave-per-i, no atomics: 183us (L2-BW 29.3 TB/s ~85% ceiling).
// R11: 2 i's/wave: 155us, VALUBusy 77%, occ 33% -> issue+latency bound
//      (VGPR 64, only 4 waves/SIMD resident; floor ~92us: 55 trans + 37 VALU).
// R12: j-split x2 -> 8192 waves (8 blocks/CU), partial*heg atomicAdd into out
//      (262k atomics, ~2 per address: harmless); prep regridded 32x256->128x64.
// Builtins: exp2 = __builtin_amdgcn_exp2f, log2 = __builtin_amdgcn_logf.

#define N_PTS 8192
#define M_PTS 8192
#define NBASIS 16
#define WIDTH 32

__device__ __forceinline__ float exp2_hw(float x) { return __builtin_amdgcn_exp2f(x); }
__device__ __forceinline__ float log2_hw(float x) { return __builtin_amdgcn_logf(x); }

__device__ __forceinline__ float fast_tanh(float z) {
    float a = fabsf(z);
    float t = __expf(-2.0f * a);
    float r = (1.0f - t) / (1.0f + t);
    return copysignf(r, z);
}

__device__ __forceinline__ float log_cosh_f(float x) {
    float a = fabsf(x);
    return a + __logf(1.0f + __expf(-2.0f * a)) - 0.6931471805599453f;
}

// ---------------- Stage 1: per-source-point quantities ----------------
// 64-thread blocks x 128 -> spread over 128 CUs (was 32 blocks: 87% idle GPU).
// cw[j]        = (cx, cy, cz, wrho)
// bnq[q*N + j] = float4{ bn[j][4q..4q+3] }, bn = -log2(e)*beta (q-plane layout)
// hegf[0..15]  = log_cosh(embed(0))^1.5
__global__ __launch_bounds__(64)
void cg_prep(const float* __restrict__ rho,
             const float* __restrict__ gamma,
             const float* __restrict__ coords,
             const float* __restrict__ weights,
             const float* __restrict__ w1,
             const float* __restrict__ b1,
             const float* __restrict__ w2,
             const float* __restrict__ b2,
             float4* __restrict__ cw,
             float4* __restrict__ bnq,
             float* __restrict__ hegf)
{
    const float PI_F = 3.14159265358979323846f;
    const float LOG2E = 1.4426950408889634f;

    __shared__ float s_w1[WIDTH], s_b1[WIDTH], s_w2[WIDTH * NBASIS], s_b2[NBASIS];
    int t = threadIdx.x;
    if (t < WIDTH) { s_w1[t] = w1[t]; s_b1[t] = b1[t]; }
    if (t < NBASIS) s_b2[t] = b2[t];
    #pragma unroll
    for (int k = 0; k < 8; ++k) s_w2[t + 64 * k] = w2[t + 64 * k];
    __syncthreads();

    int j = blockIdx.x * 64 + t;
    {
        float r = rho[j];
        float g = gamma[j];
        const float c83 = 38.28312007948569f;              // 4*(3*pi^2)^(2/3)
        float r83 = exp2_hw(2.6666666667f * log2_hw(r));   // r^(8/3)
        float s2 = g / (c83 * r83);
        float x = __logf(s2 + 1e-4f);

        float emb[NBASIS];
        #pragma unroll
        for (int b = 0; b < NBASIS; ++b) emb[b] = s_b2[b];
        #pragma unroll 4
        for (int w = 0; w < WIDTH; ++w) {
            float h = fast_tanh(fmaf(x, s_w1[w], s_b1[w]));
            #pragma unroll
            for (int b = 0; b < NBASIS; ++b)
                emb[b] = fmaf(h, s_w2[w * NBASIS + b], emb[b]);
        }
        float pref = PI_F * exp2_hw(0.6666666667f * log2_hw(0.5f * r));
        float scale = -LOG2E * pref;
        #pragma unroll
        for (int q = 0; q < 4; ++q) {
            bnq[q * N_PTS + j] = make_float4(scale * log_cosh_f(emb[4 * q + 0]),
                                             scale * log_cosh_f(emb[4 * q + 1]),
                                             scale * log_cosh_f(emb[4 * q + 2]),
                                             scale * log_cosh_f(emb[4 * q + 3]));
        }

        cw[j] = make_float4(coords[j * 3 + 0],
                            coords[j * 3 + 1],
                            coords[j * 3 + 2],
                            weights[j] * r);
    }

    if (blockIdx.x == 0 && t == 0) {
        float emb0[NBASIS];
        #pragma unroll
        for (int b = 0; b < NBASIS; ++b) emb0[b] = s_b2[b];
        for (int w = 0; w < WIDTH; ++w) {
            float h = fast_tanh(s_b1[w]);   // x = 0
            #pragma unroll
            for (int b = 0; b < NBASIS; ++b)
                emb0[b] = fmaf(h, s_w2[w * NBASIS + b], emb0[b]);
        }
        #pragma unroll
        for (int b = 0; b < NBASIS; ++b) {
            float lc = fmaxf(log_cosh_f(emb0[b]), 0.0f);
            hegf[b] = lc * sqrtf(lc);       // lc^1.5
        }
    }
}

// ---------------- Stage 2: all-pairs, 2 i's per wave, j-range split x2 ----
// wave id w in [0,8192): pair = w>>1 owns (i0,i1) = (2*pair, 2*pair+1);
// half = w&1 selects j in [half*4096, half*4096+4096). Lane L handles
// j = base + 64k + L. Butterfly-reduce, then lane 0 atomicAdds partial*heg
// into out (out pre-zeroed; ~2 colliding waves per address).
// 2048 blocks = 8 blocks/CU -> up to 32 waves/CU at VGPR<=64.
__global__ __launch_bounds__(256, 4)
void cg_pairs(const float* __restrict__ oc,
              const float4* __restrict__ cw,
              const float4* __restrict__ bnq,
              const float* __restrict__ hegf,
              float* __restrict__ out)
{
    int wid  = (blockIdx.x << 2) | (threadIdx.x >> 6);   // 0..8191
    int lane = threadIdx.x & 63;
    int pair = wid >> 1;
    int half = wid & 1;
    int i0 = pair << 1;
    int i1 = i0 | 1;
    int jbase = half << 12;                               // 0 or 4096

    float ox0 = oc[i0 * 3 + 0], oy0 = oc[i0 * 3 + 1], oz0 = oc[i0 * 3 + 2];
    float ox1 = oc[i1 * 3 + 0], oy1 = oc[i1 * 3 + 1], oz1 = oc[i1 * 3 + 2];

    float acc0[NBASIS], acc1[NBASIS];
    #pragma unroll
    for (int b = 0; b < NBASIS; ++b) { acc0[b] = 0.0f; acc1[b] = 0.0f; }

    #pragma unroll 2
    for (int k = 0; k < 64; ++k) {
        int j = jbase + (k << 6) + lane;         // lane-consecutive: coalesced
        float4 c = cw[j];
        float dx0 = ox0 - c.x, dy0 = oy0 - c.y, dz0 = oz0 - c.z;
        float dx1 = ox1 - c.x, dy1 = oy1 - c.y, dz1 = oz1 - c.z;
        float d20 = fmaf(dx0, dx0, fmaf(dy0, dy0, dz0 * dz0));
        float d21 = fmaf(dx1, dx1, fmaf(dy1, dy1, dz1 * dz1));
        #pragma unroll
        for (int q = 0; q < 4; ++q) {
            float4 b4 = bnq[q * N_PTS + j];      // coalesced dwordx4
            float e00 = exp2_hw(b4.x * d20);
            float e01 = exp2_hw(b4.y * d20);
            float e02 = exp2_hw(b4.z * d20);
            float e03 = exp2_hw(b4.w * d20);
            float e10 = exp2_hw(b4.x * d21);
            float e11 = exp2_hw(b4.y * d21);
            float e12 = exp2_hw(b4.z * d21);
            float e13 = exp2_hw(b4.w * d21);
            acc0[q * 4 + 0] = fmaf(e00, c.w, acc0[q * 4 + 0]);
            acc0[q * 4 + 1] = fmaf(e01, c.w, acc0[q * 4 + 1]);
            acc0[q * 4 + 2] = fmaf(e02, c.w, acc0[q * 4 + 2]);
            acc0[q * 4 + 3] = fmaf(e03, c.w, acc0[q * 4 + 3]);
            acc1[q * 4 + 0] = fmaf(e10, c.w, acc1[q * 4 + 0]);
            acc1[q * 4 + 1] = fmaf(e11, c.w, acc1[q * 4 + 1]);
            acc1[q * 4 + 2] = fmaf(e12, c.w, acc1[q * 4 + 2]);
            acc1[q * 4 + 3] = fmaf(e13, c.w, acc1[q * 4 + 3]);
        }
    }

    // 6-step butterfly over 64 lanes, 32 values
    #pragma unroll
    for (int m = 1; m < 64; m <<= 1) {
        #pragma unroll
        for (int b = 0; b < NBASIS; ++b) {
            acc0[b] += __shfl_xor(acc0[b], m, 64);
            acc1[b] += __shfl_xor(acc1[b], m, 64);
        }
    }

    if (lane == 0) {
        #pragma unroll
        for (int b = 0; b < NBASIS; ++b) {
            float h = hegf[b];                   // wave-uniform s_load
            atomicAdd(&out[i0 * NBASIS + b], acc0[b] * h);
            atomicAdd(&out[i1 * NBASIS + b], acc1[b] * h);
        }
    }
}

extern "C" void kernel_launch(void* const* d_in, const int* in_sizes, int n_in,
                              void* d_out, int out_size, void* d_ws, size_t ws_size,
                              hipStream_t stream) {
    const float* rho        = (const float*)d_in[0];
    const float* gamma      = (const float*)d_in[1];
    const float* coords     = (const float*)d_in[2];
    const float* weights    = (const float*)d_in[3];
    const float* out_coords = (const float*)d_in[4];
    const float* w1         = (const float*)d_in[5];
    const float* b1         = (const float*)d_in[6];
    const float* w2         = (const float*)d_in[7];
    const float* b2         = (const float*)d_in[8];

    char* ws = (char*)d_ws;
    // ws layout (640 KiB + 64 B):
    //   cw   : N * float4              = 128 KiB  @ 0
    //   bnq  : 4 planes * N * float4   = 512 KiB  @ 128K
    //   hegf : 16 * float                          @ 640K
    float4* cw   = (float4*)(ws);
    float4* bnq  = (float4*)(ws + (128 << 10));
    float*  hegf = (float*) (ws + (640 << 10));

    (void)hipMemsetAsync(d_out, 0, (size_t)M_PTS * NBASIS * sizeof(float), stream);

    cg_prep<<<N_PTS / 64, 64, 0, stream>>>(rho, gamma, coords, weights,
                                           w1, b1, w2, b2,
                                           cw, bnq, hegf);

    cg_pairs<<<M_PTS / 4, 256, 0, stream>>>(out_coords, cw, bnq, hegf,
                                            (float*)d_out);
}

// Round 13
// 190.625 us; speedup vs baseline: 1.2327x; 1.2327x over previous
//
#include <hip/hip_runtime.h>
#include <hip/hip_bf16.h>

// CoarseGraining: y[i,b] = heg[b] * sum_j exp(-beta[j,b] * d2(i,j)) * wrho[j]
// N = M = 8192, NB = 16, WIDTH = 32. Inputs float32, output float32.
// R10 wave-per-i: 183us. R11 2 i's/wave: 155us (busy 119us). R12 j-split x2:
// 181us REGRESSION -> TLP exhausted (occ capped ~12 waves/CU at VGPR 64);
// path forward = fewer executed cycles, not more waves.
// R13: R11 structure + float2-packed math (v_pk_mul/fma_f32, full-rate on
// CDNA4): all i0/i1-duplicated scalar ops become one packed op. No atomics,
// no memset, 2 dispatches.
// Builtins: exp2 = __builtin_amdgcn_exp2f, log2 = __builtin_amdgcn_logf.

#define N_PTS 8192
#define M_PTS 8192
#define NBASIS 16
#define WIDTH 32

typedef float v2f __attribute__((ext_vector_type(2)));

__device__ __forceinline__ float exp2_hw(float x) { return __builtin_amdgcn_exp2f(x); }
__device__ __forceinline__ float log2_hw(float x) { return __builtin_amdgcn_logf(x); }

__device__ __forceinline__ float fast_tanh(float z) {
    float a = fabsf(z);
    float t = __expf(-2.0f * a);
    float r = (1.0f - t) / (1.0f + t);
    return copysignf(r, z);
}

__device__ __forceinline__ float log_cosh_f(float x) {
    float a = fabsf(x);
    return a + __logf(1.0f + __expf(-2.0f * a)) - 0.6931471805599453f;
}

// ---------------- Stage 1: per-source-point quantities ----------------
// 128 blocks x 64 threads -> spread across CUs (prep latency minimized).
// cw[j]        = (cx, cy, cz, wrho)
// bnq[q*N + j] = float4{ bn[j][4q..4q+3] }, bn = -log2(e)*beta (q-plane layout)
// hegf[0..15]  = log_cosh(embed(0))^1.5
__global__ __launch_bounds__(64)
void cg_prep(const float* __restrict__ rho,
             const float* __restrict__ gamma,
             const float* __restrict__ coords,
             const float* __restrict__ weights,
             const float* __restrict__ w1,
             const float* __restrict__ b1,
             const float* __restrict__ w2,
             const float* __restrict__ b2,
             float4* __restrict__ cw,
             float4* __restrict__ bnq,
             float* __restrict__ hegf)
{
    const float PI_F = 3.14159265358979323846f;
    const float LOG2E = 1.4426950408889634f;

    __shared__ float s_w1[WIDTH], s_b1[WIDTH], s_w2[WIDTH * NBASIS], s_b2[NBASIS];
    int t = threadIdx.x;
    if (t < WIDTH) { s_w1[t] = w1[t]; s_b1[t] = b1[t]; }
    if (t < NBASIS) s_b2[t] = b2[t];
    #pragma unroll
    for (int k = 0; k < 8; ++k) s_w2[t + 64 * k] = w2[t + 64 * k];
    __syncthreads();

    int j = blockIdx.x * 64 + t;
    {
        float r = rho[j];
        float g = gamma[j];
        const float c83 = 38.28312007948569f;              // 4*(3*pi^2)^(2/3)
        float r83 = exp2_hw(2.6666666667f * log2_hw(r));   // r^(8/3)
        float s2 = g / (c83 * r83);
        float x = __logf(s2 + 1e-4f);

        float emb[NBASIS];
        #pragma unroll
        for (int b = 0; b < NBASIS; ++b) emb[b] = s_b2[b];
        #pragma unroll 4
        for (int w = 0; w < WIDTH; ++w) {
            float h = fast_tanh(fmaf(x, s_w1[w], s_b1[w]));
            #pragma unroll
            for (int b = 0; b < NBASIS; ++b)
                emb[b] = fmaf(h, s_w2[w * NBASIS + b], emb[b]);
        }
        float pref = PI_F * exp2_hw(0.6666666667f * log2_hw(0.5f * r));
        float scale = -LOG2E * pref;
        #pragma unroll
        for (int q = 0; q < 4; ++q) {
            bnq[q * N_PTS + j] = make_float4(scale * log_cosh_f(emb[4 * q + 0]),
                                             scale * log_cosh_f(emb[4 * q + 1]),
                                             scale * log_cosh_f(emb[4 * q + 2]),
                                             scale * log_cosh_f(emb[4 * q + 3]));
        }

        cw[j] = make_float4(coords[j * 3 + 0],
                            coords[j * 3 + 1],
                            coords[j * 3 + 2],
                            weights[j] * r);
    }

    if (blockIdx.x == 0 && t == 0) {
        float emb0[NBASIS];
        #pragma unroll
        for (int b = 0; b < NBASIS; ++b) emb0[b] = s_b2[b];
        for (int w = 0; w < WIDTH; ++w) {
            float h = fast_tanh(s_b1[w]);   // x = 0
            #pragma unroll
            for (int b = 0; b < NBASIS; ++b)
                emb0[b] = fmaf(h, s_w2[w * NBASIS + b], emb0[b]);
        }
        #pragma unroll
        for (int b = 0; b < NBASIS; ++b) {
            float lc = fmaxf(log_cosh_f(emb0[b]), 0.0f);
            hegf[b] = lc * sqrtf(lc);       // lc^1.5
        }
    }
}

// ---------------- Stage 2: all-pairs, 2 i's/wave, float2-packed ----------
// wave w owns i0=2w, i1=2w+1; lane L handles j = 64k+L. All per-i-duplicated
// math is v2f -> v_pk_mul/fma_f32. Butterfly-reduce 16 v2f accs, lane 0
// stores both i's with heg fused. 1024 blocks x 4 waves = 4096 waves.
__global__ __launch_bounds__(256, 4)
void cg_pairs(const float* __restrict__ oc,
              const float4* __restrict__ cw,
              const float4* __restrict__ bnq,
              const float* __restrict__ hegf,
              float* __restrict__ out)
{
    int wave = (blockIdx.x << 2) | (threadIdx.x >> 6);
    int lane = threadIdx.x & 63;
    int i0 = wave << 1;
    int i1 = i0 | 1;

    v2f oxv = { oc[i0 * 3 + 0], oc[i1 * 3 + 0] };
    v2f oyv = { oc[i0 * 3 + 1], oc[i1 * 3 + 1] };
    v2f ozv = { oc[i0 * 3 + 2], oc[i1 * 3 + 2] };

    v2f acc[NBASIS];
    #pragma unroll
    for (int b = 0; b < NBASIS; ++b) acc[b] = (v2f)0.0f;

    #pragma unroll 2
    for (int k = 0; k < N_PTS / 64; ++k) {
        int j = (k << 6) | lane;                 // lane-consecutive: coalesced
        float4 c = cw[j];
        v2f dx = oxv - c.x;                      // pk_add (scalar broadcast)
        v2f dy = oyv - c.y;
        v2f dz = ozv - c.z;
        v2f d2 = dx * dx + dy * dy + dz * dz;    // pk_mul + 2x pk_fma
        #pragma unroll
        for (int q = 0; q < 4; ++q) {
            float4 b4 = bnq[q * N_PTS + j];      // coalesced dwordx4
            v2f p0 = b4.x * d2;                  // pk_mul
            v2f p1 = b4.y * d2;
            v2f p2 = b4.z * d2;
            v2f p3 = b4.w * d2;
            v2f e0 = { exp2_hw(p0.x), exp2_hw(p0.y) };
            v2f e1 = { exp2_hw(p1.x), exp2_hw(p1.y) };
            v2f e2 = { exp2_hw(p2.x), exp2_hw(p2.y) };
            v2f e3 = { exp2_hw(p3.x), exp2_hw(p3.y) };
            acc[q * 4 + 0] += e0 * c.w;          // pk_fma
            acc[q * 4 + 1] += e1 * c.w;
            acc[q * 4 + 2] += e2 * c.w;
            acc[q * 4 + 3] += e3 * c.w;
        }
    }

    // 6-step butterfly over 64 lanes, 16 v2f values
    #pragma unroll
    for (int m = 1; m < 64; m <<= 1) {
        #pragma unroll
        for (int b = 0; b < NBASIS; ++b) {
            v2f other = { __shfl_xor(acc[b].x, m, 64),
                          __shfl_xor(acc[b].y, m, 64) };
            acc[b] += other;
        }
    }

    if (lane == 0) {
        #pragma unroll
        for (int b = 0; b < NBASIS; ++b) {
            float h = hegf[b];                   // wave-uniform s_load
            out[i0 * NBASIS + b] = acc[b].x * h;
            out[i1 * NBASIS + b] = acc[b].y * h;
        }
    }
}

extern "C" void kernel_launch(void* const* d_in, const int* in_sizes, int n_in,
                              void* d_out, int out_size, void* d_ws, size_t ws_size,
                              hipStream_t stream) {
    const float* rho        = (const float*)d_in[0];
    const float* gamma      = (const float*)d_in[1];
    const float* coords     = (const float*)d_in[2];
    const float* weights    = (const float*)d_in[3];
    const float* out_coords = (const float*)d_in[4];
    const float* w1         = (const float*)d_in[5];
    const float* b1         = (const float*)d_in[6];
    const float* w2         = (const float*)d_in[7];
    const float* b2         = (const float*)d_in[8];

    char* ws = (char*)d_ws;
    // ws layout (640 KiB + 64 B):
    //   cw   : N * float4              = 128 KiB  @ 0
    //   bnq  : 4 planes * N * float4   = 512 KiB  @ 128K
    //   hegf : 16 * float                          @ 640K
    float4* cw   = (float4*)(ws);
    float4* bnq  = (float4*)(ws + (128 << 10));
    float*  hegf = (float*) (ws + (640 << 10));

    cg_prep<<<N_PTS / 64, 64, 0, stream>>>(rho, gamma, coords, weights,
                                           w1, b1, w2, b2,
                                           cw, bnq, hegf);

    cg_pairs<<<M_PTS / 8, 256, 0, stream>>>(out_coords, cw, bnq, hegf,
                                            (float*)d_out);
}